// Round 9
// baseline (425.332 us; speedup 1.0000x reference)
//
#include <hip/hip_runtime.h>

#define VN     5023
#define NBETA  150
#define NBP    152          // padded K: 0..149 betas-dirs, 150 = v_template, 151 = 0
#define NBATCH 1024
#define N3     15069        // V*3
#define BT     8            // batches per block in K3 (16 -> 8: occupancy 20 -> 32 waves/CU)
#define K1_CHUNK 40

typedef float f32x4 __attribute__((ext_vector_type(4)));   // native vector: OK for nontemporal builtins

// ---- K0: build sdp[N3][NBP] (cols 0..149 = shapedirs, col 150 = v_template, 151 = 0);
//      also zero JS (first 15*NBP threads). k1_js runs after -> ordering safe.
__global__ void k0_pad(const float* __restrict__ sd, const float* __restrict__ vt,
                       float* __restrict__ sdp, float* __restrict__ JS) {
    int i = blockIdx.x * 256 + threadIdx.x;
    if (i < 15 * NBP) JS[i] = 0.0f;
    if (i >= N3 * NBP) return;
    int row = i / NBP, l = i - row * NBP;
    float val = 0.0f;
    if (l < NBETA) val = sd[row * NBETA + l];
    else if (l == NBETA) val = vt[row];   // v_template folded into column 150
    sdp[i] = val;
}

// ---- K1: JS[j3c][l] += sum_v jr[j,v] * sdp[v*3+c][l]  (col 150 gives Jt for free)
__global__ void k1_js(const float* __restrict__ jr, const float* __restrict__ sdp,
                      float* __restrict__ JS) {
    int j3c = blockIdx.x;              // 0..14
    int j = j3c / 3, c = j3c - 3 * j;
    int l = threadIdx.x;
    if (l >= NBP) return;
    int v0 = blockIdx.y * K1_CHUNK, v1 = min(v0 + K1_CHUNK, VN);
    float acc = 0.0f;
    for (int v = v0; v < v1; ++v)
        acc += jr[j * VN + v] * sdp[(size_t)(v * 3 + c) * NBP + l];
    atomicAdd(&JS[j3c * NBP + l], acc);
}

// ---- rodrigues (matches reference eps semantics) ----
__device__ __forceinline__ void rodrigues3(float x, float y, float z, float* R) {
    float ax = x + 1e-8f, ay = y + 1e-8f, az = z + 1e-8f;
    float ang = sqrtf(ax * ax + ay * ay + az * az);
    float inv = 1.0f / ang;
    float ux = x * inv, uy = y * inv, uz = z * inv;
    float co = cosf(ang), si = sinf(ang), t1 = 1.0f - co;
    float K[9] = {0.f, -uz, uy,  uz, 0.f, -ux,  -uy, ux, 0.f};
    float K2[9];
#pragma unroll
    for (int r = 0; r < 3; r++)
#pragma unroll
        for (int cc = 0; cc < 3; cc++) {
            float a = 0.f;
#pragma unroll
            for (int k = 0; k < 3; k++) a += K[r * 3 + k] * K[k * 3 + cc];
            K2[r * 3 + cc] = a;
        }
#pragma unroll
    for (int i = 0; i < 9; i++) {
        float e = (i == 0 || i == 4 || i == 8) ? 1.f : 0.f;
        R[i] = e + si * K[i] + t1 * K2[i];
    }
}

// ---- K2: per-batch betas (col150=1, col151=0), joints = JS.sB, chain, rel, pf9 ----
__global__ void k2_pose(const float* __restrict__ shp, const float* __restrict__ expr,
                        const float* __restrict__ pose, const float* __restrict__ JS,
                        float* __restrict__ betasF, float* __restrict__ pf9,
                        float* __restrict__ rel) {
    int b = blockIdx.x;
    int tt = threadIdx.x;
    __shared__ float sB[NBP];
    __shared__ float sJ[15];
    for (int l = tt; l < NBP; l += 64) {
        float val = 0.0f;
        if (l < 100) val = shp[b * 100 + l];
        else if (l < 150) val = expr[b * 50 + (l - 100)];
        else if (l == 150) val = 1.0f;   // picks up v_template / Jt columns
        sB[l] = val;
        betasF[b * NBP + l] = val;
    }
    __syncthreads();
    if (tt < 15) {
        float acc = 0.0f;
        const float* row = JS + tt * NBP;
        for (int l = 0; l < NBP; ++l) acc += row[l] * sB[l];
        sJ[tt] = acc;
    }
    __syncthreads();
    if (tt == 0) {
        float p[6];
#pragma unroll
        for (int i = 0; i < 6; i++) p[i] = pose[b * 6 + i];
        float R0[9], RJ[9];
        rodrigues3(p[0], p[1], p[2], R0);
        rodrigues3(p[3], p[4], p[5], RJ);
        float Jm[5][3];
#pragma unroll
        for (int jj = 0; jj < 5; jj++)
#pragma unroll
            for (int cc = 0; cc < 3; cc++) Jm[jj][cc] = sJ[jj * 3 + cc];
        float rj[5][3];
#pragma unroll
        for (int cc = 0; cc < 3; cc++) {
            rj[0][cc] = Jm[0][cc];
            rj[1][cc] = Jm[1][cc] - Jm[0][cc];
            rj[2][cc] = Jm[2][cc] - Jm[1][cc];
            rj[3][cc] = Jm[3][cc] - Jm[1][cc];
            rj[4][cc] = Jm[4][cc] - Jm[1][cc];
        }
        float tw[5][3];
#pragma unroll
        for (int cc = 0; cc < 3; cc++) tw[0][cc] = rj[0][cc];
#pragma unroll
        for (int cc = 0; cc < 3; cc++)
            tw[1][cc] = R0[cc * 3 + 0] * rj[1][0] + R0[cc * 3 + 1] * rj[1][1] + R0[cc * 3 + 2] * rj[1][2] + tw[0][cc];
#pragma unroll
        for (int jj = 2; jj < 5; jj++)
#pragma unroll
            for (int cc = 0; cc < 3; cc++)
                tw[jj][cc] = R0[cc * 3 + 0] * rj[jj][0] + R0[cc * 3 + 1] * rj[jj][1] + R0[cc * 3 + 2] * rj[jj][2] + tw[1][cc];
        float R2w[9];
#pragma unroll
        for (int r = 0; r < 3; r++)
#pragma unroll
            for (int cc = 0; cc < 3; cc++) {
                float a = 0.f;
#pragma unroll
                for (int k = 0; k < 3; k++) a += R0[r * 3 + k] * RJ[k * 3 + cc];
                R2w[r * 3 + cc] = a;
            }
        float* ro = rel + b * 80;
#pragma unroll
        for (int jj = 0; jj < 5; jj++) {
            const float* Rw = (jj == 2) ? R2w : R0;
#pragma unroll
            for (int rr = 0; rr < 3; rr++) {
                ro[jj * 16 + rr * 4 + 0] = Rw[rr * 3 + 0];
                ro[jj * 16 + rr * 4 + 1] = Rw[rr * 3 + 1];
                ro[jj * 16 + rr * 4 + 2] = Rw[rr * 3 + 2];
                float tj = Rw[rr * 3 + 0] * Jm[jj][0] + Rw[rr * 3 + 1] * Jm[jj][1] + Rw[rr * 3 + 2] * Jm[jj][2];
                ro[jj * 16 + rr * 4 + 3] = tw[jj][rr] - tj;
            }
            ro[jj * 16 + 12] = 0.f; ro[jj * 16 + 13] = 0.f; ro[jj * 16 + 14] = 0.f; ro[jj * 16 + 15] = 1.f;
        }
        float* pf = pf9 + b * 12;
#pragma unroll
        for (int e = 0; e < 9; e++) pf[e] = RJ[e] - ((e == 0 || e == 4 || e == 8) ? 1.f : 0.f);
        pf[9] = 0.f; pf[10] = 0.f; pf[11] = 0.f;
    }
}

// ---- K3: fused blendshape GEMM + pose blend + LBS ----
// BT=8: LDS 7.8 KB -> 16 blocks/CU (VGPR-capped) = 32 waves/CU.
// Non-temporal output stores: keep 437 MB of streaming writes out of L2/L3
// so the 9.2 MB sdp panel stays cache-resident across grid.y re-reads.
__global__ void k3_main(const float* __restrict__ sdp, const float* __restrict__ pd,
                        const float* __restrict__ lw,
                        const float* __restrict__ betasF, const float* __restrict__ pf9,
                        const float* __restrict__ rel,
                        float* __restrict__ outv, float* __restrict__ outT) {
    __shared__ float sBet[BT][NBP];   // 4864 B
    __shared__ float sRel[BT][80];    // 2560 B
    __shared__ float sPf[BT][12];     // 384 B

    int tid = threadIdx.x;
    int v = blockIdx.x * 128 + tid;
    bool ok = v < VN;
    int vc = ok ? v : 0;
    int b0 = blockIdx.y * BT;

    for (int i = tid; i < BT * NBP; i += 128) {
        int bb = i / NBP, l = i - bb * NBP;
        sBet[bb][l] = betasF[(size_t)(b0 + bb) * NBP + l];
    }
    for (int i = tid; i < BT * 80; i += 128) {
        int bb = i / 80, e = i - bb * 80;
        sRel[bb][e] = rel[(size_t)(b0 + bb) * 80 + e];
    }
    if (tid < BT * 12) {
        int bb = tid / 12, e = tid - bb * 12;
        sPf[bb][e] = pf9[(size_t)(b0 + bb) * 12 + e];
    }
    __syncthreads();

    float acc[3][BT];
#pragma unroll
    for (int c = 0; c < 3; c++)
#pragma unroll
        for (int bb = 0; bb < BT; bb++) acc[c][bb] = 0.0f;

    const float* srow = sdp + (size_t)vc * 3 * NBP;

#pragma unroll 1
    for (int l0 = 0; l0 < NBP; l0 += 8) {
        const float4 a0  = *(const float4*)(srow + l0);
        const float4 a1  = *(const float4*)(srow + l0 + 4);
        const float4 bq0 = *(const float4*)(srow + NBP + l0);
        const float4 bq1 = *(const float4*)(srow + NBP + l0 + 4);
        const float4 cq0 = *(const float4*)(srow + 2 * NBP + l0);
        const float4 cq1 = *(const float4*)(srow + 2 * NBP + l0 + 4);
        float s0[8] = {a0.x, a0.y, a0.z, a0.w, a1.x, a1.y, a1.z, a1.w};
        float s1[8] = {bq0.x, bq0.y, bq0.z, bq0.w, bq1.x, bq1.y, bq1.z, bq1.w};
        float s2[8] = {cq0.x, cq0.y, cq0.z, cq0.w, cq1.x, cq1.y, cq1.z, cq1.w};
#pragma unroll
        for (int bb = 0; bb < BT; bb++) {
            const float4 be0 = *(const float4*)(&sBet[bb][l0]);
            const float4 be1 = *(const float4*)(&sBet[bb][l0 + 4]);
            float be[8] = {be0.x, be0.y, be0.z, be0.w, be1.x, be1.y, be1.z, be1.w};
#pragma unroll
            for (int k = 0; k < 8; k++) {
                acc[0][bb] += be[k] * s0[k];
                acc[1][bb] += be[k] * s1[k];
                acc[2][bb] += be[k] * s2[k];
            }
        }
    }

    if (!ok) return;

    float wj[5], pdv[9][3];
#pragma unroll
    for (int j = 0; j < 5; j++) wj[j] = lw[v * 5 + j];
#pragma unroll
    for (int k = 0; k < 9; k++)
#pragma unroll
        for (int c = 0; c < 3; c++) pdv[k][c] = pd[(size_t)(9 + k) * N3 + v * 3 + c];

#pragma unroll    // full unroll: acc must stay register-indexed
    for (int bb = 0; bb < BT; bb++) {
        int b = b0 + bb;
        float vp[3];
#pragma unroll
        for (int c = 0; c < 3; c++) {
            float x = acc[c][bb];                     // = v_shaped (template folded in)
#pragma unroll
            for (int k = 0; k < 9; k++) x += sPf[bb][k] * pdv[k][c];
            vp[c] = x;
        }
        float T[16];
#pragma unroll
        for (int e = 0; e < 16; e++) T[e] = 0.0f;
#pragma unroll
        for (int j = 0; j < 5; j++) {
            float w = wj[j];
            const float4* rj4 = (const float4*)(&sRel[bb][j * 16]);
            float4 r0 = rj4[0], r1 = rj4[1], r2 = rj4[2], r3 = rj4[3];
            T[0]  += w * r0.x;  T[1]  += w * r0.y;  T[2]  += w * r0.z;  T[3]  += w * r0.w;
            T[4]  += w * r1.x;  T[5]  += w * r1.y;  T[6]  += w * r1.z;  T[7]  += w * r1.w;
            T[8]  += w * r2.x;  T[9]  += w * r2.y;  T[10] += w * r2.z;  T[11] += w * r2.w;
            T[12] += w * r3.x;  T[13] += w * r3.y;  T[14] += w * r3.z;  T[15] += w * r3.w;
        }
        float vo[3];
#pragma unroll
        for (int rr = 0; rr < 3; rr++)
            vo[rr] = T[rr * 4 + 0] * vp[0] + T[rr * 4 + 1] * vp[1] + T[rr * 4 + 2] * vp[2] + T[rr * 4 + 3];

        size_t vbase = (size_t)b * VN + v;
        float* pv = outv + vbase * 3;
        __builtin_nontemporal_store(vo[0], pv + 0);
        __builtin_nontemporal_store(vo[1], pv + 1);
        __builtin_nontemporal_store(vo[2], pv + 2);
        f32x4* pT = (f32x4*)(outT + vbase * 16);   // native ext_vector: accepted by the builtin
        f32x4 t0 = {T[0],  T[1],  T[2],  T[3]};
        f32x4 t1 = {T[4],  T[5],  T[6],  T[7]};
        f32x4 t2 = {T[8],  T[9],  T[10], T[11]};
        f32x4 t3 = {T[12], T[13], T[14], T[15]};
        __builtin_nontemporal_store(t0, pT + 0);
        __builtin_nontemporal_store(t1, pT + 1);
        __builtin_nontemporal_store(t2, pT + 2);
        __builtin_nontemporal_store(t3, pT + 3);
    }
}

// ---------------- launch ----------------
extern "C" void kernel_launch(void* const* d_in, const int* in_sizes, int n_in,
                              void* d_out, int out_size, void* d_ws, size_t ws_size,
                              hipStream_t stream) {
    const float* shp  = (const float*)d_in[0];  // [1024,100]
    const float* expr = (const float*)d_in[1];  // [1024,50]
    const float* pose = (const float*)d_in[2];  // [1024,6]
    const float* vt   = (const float*)d_in[3];  // [5023,3]
    const float* sd   = (const float*)d_in[4];  // [5023,3,150]
    const float* pd   = (const float*)d_in[5];  // [36,15069]
    const float* jr   = (const float*)d_in[6];  // [5,5023]
    const float* lw   = (const float*)d_in[7];  // [5023,5]

    float* outv = (float*)d_out;
    float* outT = outv + (size_t)NBATCH * VN * 3;

    char* w = (char*)d_ws;
    const size_t SDP_B   = (size_t)N3 * NBP * 4;            // 9,161,952
    const size_t JS_B    = 15 * NBP * 4;                    // 9,120
    const size_t BETAS_B = (size_t)NBATCH * NBP * 4;        // 622,592
    const size_t PF9_B   = (size_t)NBATCH * 12 * 4;         // 49,152
    float* sdp    = (float*)w;
    float* JS     = (float*)(w + SDP_B);
    float* betasF = (float*)(w + SDP_B + JS_B);
    float* pf9    = (float*)(w + SDP_B + JS_B + BETAS_B);
    float* rel    = (float*)(w + SDP_B + JS_B + BETAS_B + PF9_B);

    k0_pad<<<(N3 * NBP + 255) / 256, 256, 0, stream>>>(sd, vt, sdp, JS);
    k1_js<<<dim3(15, (VN + K1_CHUNK - 1) / K1_CHUNK), 192, 0, stream>>>(jr, sdp, JS);
    k2_pose<<<NBATCH, 64, 0, stream>>>(shp, expr, pose, JS, betasF, pf9, rel);
    k3_main<<<dim3(40, NBATCH / BT), 128, 0, stream>>>(sdp, pd, lw, betasF, pf9, rel, outv, outT);
}

// Round 10
// 302.382 us; speedup vs baseline: 1.4066x; 1.4066x over previous
//
#include <hip/hip_runtime.h>

#define VN     5023
#define NBETA  150
#define NBP    152          // padded K: 0..149 betas-dirs, 150 = v_template, 151 = 0
#define NBATCH 1024
#define N3     15069        // V*3
#define BT     8            // batches per block in K3
#define K1_CHUNK 40

// ---- K0: build sdp[N3][NBP] (cols 0..149 = shapedirs, col 150 = v_template, 151 = 0);
//      also zero JS (first 15*NBP threads). k1_js runs after -> ordering safe.
__global__ void k0_pad(const float* __restrict__ sd, const float* __restrict__ vt,
                       float* __restrict__ sdp, float* __restrict__ JS) {
    int i = blockIdx.x * 256 + threadIdx.x;
    if (i < 15 * NBP) JS[i] = 0.0f;
    if (i >= N3 * NBP) return;
    int row = i / NBP, l = i - row * NBP;
    float val = 0.0f;
    if (l < NBETA) val = sd[row * NBETA + l];
    else if (l == NBETA) val = vt[row];   // v_template folded into column 150
    sdp[i] = val;
}

// ---- K1: JS[j3c][l] += sum_v jr[j,v] * sdp[v*3+c][l]  (col 150 gives Jt for free)
__global__ void k1_js(const float* __restrict__ jr, const float* __restrict__ sdp,
                      float* __restrict__ JS) {
    int j3c = blockIdx.x;              // 0..14
    int j = j3c / 3, c = j3c - 3 * j;
    int l = threadIdx.x;
    if (l >= NBP) return;
    int v0 = blockIdx.y * K1_CHUNK, v1 = min(v0 + K1_CHUNK, VN);
    float acc = 0.0f;
    for (int v = v0; v < v1; ++v)
        acc += jr[j * VN + v] * sdp[(size_t)(v * 3 + c) * NBP + l];
    atomicAdd(&JS[j3c * NBP + l], acc);
}

// ---- rodrigues (matches reference eps semantics) ----
__device__ __forceinline__ void rodrigues3(float x, float y, float z, float* R) {
    float ax = x + 1e-8f, ay = y + 1e-8f, az = z + 1e-8f;
    float ang = sqrtf(ax * ax + ay * ay + az * az);
    float inv = 1.0f / ang;
    float ux = x * inv, uy = y * inv, uz = z * inv;
    float co = cosf(ang), si = sinf(ang), t1 = 1.0f - co;
    float K[9] = {0.f, -uz, uy,  uz, 0.f, -ux,  -uy, ux, 0.f};
    float K2[9];
#pragma unroll
    for (int r = 0; r < 3; r++)
#pragma unroll
        for (int cc = 0; cc < 3; cc++) {
            float a = 0.f;
#pragma unroll
            for (int k = 0; k < 3; k++) a += K[r * 3 + k] * K[k * 3 + cc];
            K2[r * 3 + cc] = a;
        }
#pragma unroll
    for (int i = 0; i < 9; i++) {
        float e = (i == 0 || i == 4 || i == 8) ? 1.f : 0.f;
        R[i] = e + si * K[i] + t1 * K2[i];
    }
}

// ---- K2: per-batch betas (col150=1, col151=0), joints = JS.sB, chain, rel, pf9 ----
__global__ void k2_pose(const float* __restrict__ shp, const float* __restrict__ expr,
                        const float* __restrict__ pose, const float* __restrict__ JS,
                        float* __restrict__ betasF, float* __restrict__ pf9,
                        float* __restrict__ rel) {
    int b = blockIdx.x;
    int tt = threadIdx.x;
    __shared__ float sB[NBP];
    __shared__ float sJ[15];
    for (int l = tt; l < NBP; l += 64) {
        float val = 0.0f;
        if (l < 100) val = shp[b * 100 + l];
        else if (l < 150) val = expr[b * 50 + (l - 100)];
        else if (l == 150) val = 1.0f;   // picks up v_template / Jt columns
        sB[l] = val;
        betasF[b * NBP + l] = val;
    }
    __syncthreads();
    if (tt < 15) {
        float acc = 0.0f;
        const float* row = JS + tt * NBP;
        for (int l = 0; l < NBP; ++l) acc += row[l] * sB[l];
        sJ[tt] = acc;
    }
    __syncthreads();
    if (tt == 0) {
        float p[6];
#pragma unroll
        for (int i = 0; i < 6; i++) p[i] = pose[b * 6 + i];
        float R0[9], RJ[9];
        rodrigues3(p[0], p[1], p[2], R0);
        rodrigues3(p[3], p[4], p[5], RJ);
        float Jm[5][3];
#pragma unroll
        for (int jj = 0; jj < 5; jj++)
#pragma unroll
            for (int cc = 0; cc < 3; cc++) Jm[jj][cc] = sJ[jj * 3 + cc];
        float rj[5][3];
#pragma unroll
        for (int cc = 0; cc < 3; cc++) {
            rj[0][cc] = Jm[0][cc];
            rj[1][cc] = Jm[1][cc] - Jm[0][cc];
            rj[2][cc] = Jm[2][cc] - Jm[1][cc];
            rj[3][cc] = Jm[3][cc] - Jm[1][cc];
            rj[4][cc] = Jm[4][cc] - Jm[1][cc];
        }
        float tw[5][3];
#pragma unroll
        for (int cc = 0; cc < 3; cc++) tw[0][cc] = rj[0][cc];
#pragma unroll
        for (int cc = 0; cc < 3; cc++)
            tw[1][cc] = R0[cc * 3 + 0] * rj[1][0] + R0[cc * 3 + 1] * rj[1][1] + R0[cc * 3 + 2] * rj[1][2] + tw[0][cc];
#pragma unroll
        for (int jj = 2; jj < 5; jj++)
#pragma unroll
            for (int cc = 0; cc < 3; cc++)
                tw[jj][cc] = R0[cc * 3 + 0] * rj[jj][0] + R0[cc * 3 + 1] * rj[jj][1] + R0[cc * 3 + 2] * rj[jj][2] + tw[1][cc];
        float R2w[9];
#pragma unroll
        for (int r = 0; r < 3; r++)
#pragma unroll
            for (int cc = 0; cc < 3; cc++) {
                float a = 0.f;
#pragma unroll
                for (int k = 0; k < 3; k++) a += R0[r * 3 + k] * RJ[k * 3 + cc];
                R2w[r * 3 + cc] = a;
            }
        float* ro = rel + b * 80;
#pragma unroll
        for (int jj = 0; jj < 5; jj++) {
            const float* Rw = (jj == 2) ? R2w : R0;
#pragma unroll
            for (int rr = 0; rr < 3; rr++) {
                ro[jj * 16 + rr * 4 + 0] = Rw[rr * 3 + 0];
                ro[jj * 16 + rr * 4 + 1] = Rw[rr * 3 + 1];
                ro[jj * 16 + rr * 4 + 2] = Rw[rr * 3 + 2];
                float tj = Rw[rr * 3 + 0] * Jm[jj][0] + Rw[rr * 3 + 1] * Jm[jj][1] + Rw[rr * 3 + 2] * Jm[jj][2];
                ro[jj * 16 + rr * 4 + 3] = tw[jj][rr] - tj;
            }
            ro[jj * 16 + 12] = 0.f; ro[jj * 16 + 13] = 0.f; ro[jj * 16 + 14] = 0.f; ro[jj * 16 + 15] = 1.f;
        }
        float* pf = pf9 + b * 12;
#pragma unroll
        for (int e = 0; e < 9; e++) pf[e] = RJ[e] - ((e == 0 || e == 4 || e == 8) ? 1.f : 0.f);
        pf[9] = 0.f; pf[10] = 0.f; pf[11] = 0.f;
    }
}

// ---- K3: fused blendshape GEMM + pose blend + LBS ----
// BT=8: LDS 7.8 KB -> high occupancy. Plain (write-back) stores: L2 merges the
// interleaved float4/scalar output pattern into full lines (nt stores caused
// 1.6x write amplification + RMW-slow DRAM writes in round 9).
// wj/pdv loads hoisted above the GEMM loop so their latency hides under FMA work.
__global__ void k3_main(const float* __restrict__ sdp, const float* __restrict__ pd,
                        const float* __restrict__ lw,
                        const float* __restrict__ betasF, const float* __restrict__ pf9,
                        const float* __restrict__ rel,
                        float* __restrict__ outv, float* __restrict__ outT) {
    __shared__ float sBet[BT][NBP];   // 4864 B
    __shared__ float sRel[BT][80];    // 2560 B
    __shared__ float sPf[BT][12];     // 384 B

    int tid = threadIdx.x;
    int v = blockIdx.x * 128 + tid;
    bool ok = v < VN;
    int vc = ok ? v : 0;
    int b0 = blockIdx.y * BT;

    for (int i = tid; i < BT * NBP; i += 128) {
        int bb = i / NBP, l = i - bb * NBP;
        sBet[bb][l] = betasF[(size_t)(b0 + bb) * NBP + l];
    }
    for (int i = tid; i < BT * 80; i += 128) {
        int bb = i / 80, e = i - bb * 80;
        sRel[bb][e] = rel[(size_t)(b0 + bb) * 80 + e];
    }
    if (tid < BT * 12) {
        int bb = tid / 12, e = tid - bb * 12;
        sPf[bb][e] = pf9[(size_t)(b0 + bb) * 12 + e];
    }

    // epilogue inputs issued early: latency hides under the GEMM FMA stream
    float wj[5], pdv[9][3];
#pragma unroll
    for (int j = 0; j < 5; j++) wj[j] = lw[vc * 5 + j];
#pragma unroll
    for (int k = 0; k < 9; k++)
#pragma unroll
        for (int c = 0; c < 3; c++) pdv[k][c] = pd[(size_t)(9 + k) * N3 + vc * 3 + c];

    __syncthreads();

    float acc[3][BT];
#pragma unroll
    for (int c = 0; c < 3; c++)
#pragma unroll
        for (int bb = 0; bb < BT; bb++) acc[c][bb] = 0.0f;

    const float* srow = sdp + (size_t)vc * 3 * NBP;

#pragma unroll 1
    for (int l0 = 0; l0 < NBP; l0 += 8) {
        const float4 a0  = *(const float4*)(srow + l0);
        const float4 a1  = *(const float4*)(srow + l0 + 4);
        const float4 bq0 = *(const float4*)(srow + NBP + l0);
        const float4 bq1 = *(const float4*)(srow + NBP + l0 + 4);
        const float4 cq0 = *(const float4*)(srow + 2 * NBP + l0);
        const float4 cq1 = *(const float4*)(srow + 2 * NBP + l0 + 4);
        float s0[8] = {a0.x, a0.y, a0.z, a0.w, a1.x, a1.y, a1.z, a1.w};
        float s1[8] = {bq0.x, bq0.y, bq0.z, bq0.w, bq1.x, bq1.y, bq1.z, bq1.w};
        float s2[8] = {cq0.x, cq0.y, cq0.z, cq0.w, cq1.x, cq1.y, cq1.z, cq1.w};
#pragma unroll
        for (int bb = 0; bb < BT; bb++) {
            const float4 be0 = *(const float4*)(&sBet[bb][l0]);
            const float4 be1 = *(const float4*)(&sBet[bb][l0 + 4]);
            float be[8] = {be0.x, be0.y, be0.z, be0.w, be1.x, be1.y, be1.z, be1.w};
#pragma unroll
            for (int k = 0; k < 8; k++) {
                acc[0][bb] += be[k] * s0[k];
                acc[1][bb] += be[k] * s1[k];
                acc[2][bb] += be[k] * s2[k];
            }
        }
    }

    if (!ok) return;

#pragma unroll    // full unroll: acc must stay register-indexed
    for (int bb = 0; bb < BT; bb++) {
        int b = b0 + bb;
        float vp[3];
#pragma unroll
        for (int c = 0; c < 3; c++) {
            float x = acc[c][bb];                     // = v_shaped (template folded in)
#pragma unroll
            for (int k = 0; k < 9; k++) x += sPf[bb][k] * pdv[k][c];
            vp[c] = x;
        }
        float T[16];
#pragma unroll
        for (int e = 0; e < 16; e++) T[e] = 0.0f;
#pragma unroll
        for (int j = 0; j < 5; j++) {
            float w = wj[j];
            const float4* rj4 = (const float4*)(&sRel[bb][j * 16]);
            float4 r0 = rj4[0], r1 = rj4[1], r2 = rj4[2], r3 = rj4[3];
            T[0]  += w * r0.x;  T[1]  += w * r0.y;  T[2]  += w * r0.z;  T[3]  += w * r0.w;
            T[4]  += w * r1.x;  T[5]  += w * r1.y;  T[6]  += w * r1.z;  T[7]  += w * r1.w;
            T[8]  += w * r2.x;  T[9]  += w * r2.y;  T[10] += w * r2.z;  T[11] += w * r2.w;
            T[12] += w * r3.x;  T[13] += w * r3.y;  T[14] += w * r3.z;  T[15] += w * r3.w;
        }
        float vo[3];
#pragma unroll
        for (int rr = 0; rr < 3; rr++)
            vo[rr] = T[rr * 4 + 0] * vp[0] + T[rr * 4 + 1] * vp[1] + T[rr * 4 + 2] * vp[2] + T[rr * 4 + 3];

        size_t vbase = (size_t)b * VN + v;
        float* pv = outv + vbase * 3;
        pv[0] = vo[0];
        pv[1] = vo[1];
        pv[2] = vo[2];
        float4* pT = (float4*)(outT + vbase * 16);
        pT[0] = make_float4(T[0],  T[1],  T[2],  T[3]);
        pT[1] = make_float4(T[4],  T[5],  T[6],  T[7]);
        pT[2] = make_float4(T[8],  T[9],  T[10], T[11]);
        pT[3] = make_float4(T[12], T[13], T[14], T[15]);
    }
}

// ---------------- launch ----------------
extern "C" void kernel_launch(void* const* d_in, const int* in_sizes, int n_in,
                              void* d_out, int out_size, void* d_ws, size_t ws_size,
                              hipStream_t stream) {
    const float* shp  = (const float*)d_in[0];  // [1024,100]
    const float* expr = (const float*)d_in[1];  // [1024,50]
    const float* pose = (const float*)d_in[2];  // [1024,6]
    const float* vt   = (const float*)d_in[3];  // [5023,3]
    const float* sd   = (const float*)d_in[4];  // [5023,3,150]
    const float* pd   = (const float*)d_in[5];  // [36,15069]
    const float* jr   = (const float*)d_in[6];  // [5,5023]
    const float* lw   = (const float*)d_in[7];  // [5023,5]

    float* outv = (float*)d_out;
    float* outT = outv + (size_t)NBATCH * VN * 3;

    char* w = (char*)d_ws;
    const size_t SDP_B   = (size_t)N3 * NBP * 4;            // 9,161,952
    const size_t JS_B    = 15 * NBP * 4;                    // 9,120
    const size_t BETAS_B = (size_t)NBATCH * NBP * 4;        // 622,592
    const size_t PF9_B   = (size_t)NBATCH * 12 * 4;         // 49,152
    float* sdp    = (float*)w;
    float* JS     = (float*)(w + SDP_B);
    float* betasF = (float*)(w + SDP_B + JS_B);
    float* pf9    = (float*)(w + SDP_B + JS_B + BETAS_B);
    float* rel    = (float*)(w + SDP_B + JS_B + BETAS_B + PF9_B);

    k0_pad<<<(N3 * NBP + 255) / 256, 256, 0, stream>>>(sd, vt, sdp, JS);
    k1_js<<<dim3(15, (VN + K1_CHUNK - 1) / K1_CHUNK), 192, 0, stream>>>(jr, sdp, JS);
    k2_pose<<<NBATCH, 64, 0, stream>>>(shp, expr, pose, JS, betasF, pf9, rel);
    k3_main<<<dim3(40, NBATCH / BT), 128, 0, stream>>>(sdp, pd, lw, betasF, pf9, rel, outv, outT);
}